// Round 4
// baseline (2476.419 us; speedup 1.0000x reference)
//
#include <hip/hip_runtime.h>

#define NN     10000
#define DI     128
#define DO     256
#define KNB    32
#define NSRC   33      // 32 neighbors + self
#define CHUNK  1024
#define NCHUNK 10      // NP2 / CHUNK
#define RB     16      // rows per block in distance/gemm kernels
#define NP2    10240   // padded column count (multiple of CHUNK)
#define SLOTS  48      // per-(row,chunk) candidate slots (>=32+ties)
#define MTOT   (NCHUNK * SLOTS)   // 480 candidates entering merge
#define MCAND  128     // candidates kept per row for f64 re-rank
#define NEG    0.2f

// monotone map f32 -> u32 preserving < order (handles negatives)
__device__ __forceinline__ unsigned fkey(float f) {
    unsigned u = __float_as_uint(f);
    return (u & 0x80000000u) ? ~u : (u | 0x80000000u);
}

__global__ void transpose32_k(const float* __restrict__ x, float* __restrict__ xT) {
    int j = blockIdx.x * 256 + threadIdx.x;
    int d = blockIdx.y;
    if (j < NP2) xT[(size_t)d * NP2 + j] = (j < NN) ? x[(size_t)j * DI + d] : 0.f;
}

// per-row squared norms in f64 (from coalesced xT), plus f32 copy
__global__ void sqrow_k(const float* __restrict__ xT, double* __restrict__ sq64,
                        float* __restrict__ sq32) {
    int j = blockIdx.x * 256 + threadIdx.x;
    if (j >= NP2) return;
    double s = 0.0;
    for (int d = 0; d < DI; ++d) {
        double v = (double)xT[(size_t)d * NP2 + j];
        s = fma(v, v, s);
    }
    if (j < NN) sq64[j] = s;
    sq32[j] = (j < NN) ? (float)s : 0.f;
}

// h_l = x@W_l + b_l ; h_r = x@W_r + b_r  (f32 vector FMA, 16 rows/block, col=thread)
__global__ __launch_bounds__(256) void hgemm_k(
    const float* __restrict__ x, const float* __restrict__ Wl,
    const float* __restrict__ bl, const float* __restrict__ Wr,
    const float* __restrict__ br, float* __restrict__ hl, float* __restrict__ hr)
{
    const int c = threadIdx.x;
    const int r0 = blockIdx.x * RB;
    float accl[RB], accr[RB];
    const float blv = bl[c], brv = br[c];
#pragma unroll
    for (int r = 0; r < RB; ++r) { accl[r] = blv; accr[r] = brv; }
    for (int d = 0; d < DI; ++d) {
        const float wl = Wl[d * DO + c];
        const float wr = Wr[d * DO + c];
#pragma unroll
        for (int r = 0; r < RB; ++r) {
            const float xv = x[(size_t)(r0 + r) * DI + d];  // wave-uniform
            accl[r] = fmaf(xv, wl, accl[r]);
            accr[r] = fmaf(xv, wr, accr[r]);
        }
    }
#pragma unroll
    for (int r = 0; r < RB; ++r) {
        hl[(size_t)(r0 + r) * DO + c] = accl[r];
        hr[(size_t)(r0 + r) * DO + c] = accr[r];
    }
}

// f32 distances for a 16-row x 1024-col tile; per-row per-chunk top-32 multiset
// via ballot-bisection threshold (exact 32nd-smallest key), emitted with
// ballot-prefix slots. No sorts, no serial pops.
__global__ __launch_bounds__(256, 4) void knn_partial_k(
    const float* __restrict__ x, const float* __restrict__ xT,
    const float* __restrict__ sq32, unsigned long long* __restrict__ keys)
{
    __shared__ float xs[RB * DI];               // 8 KB
    __shared__ unsigned dist4[4][CHUNK];        // 16 KB (fkey u32)

    const int r0 = blockIdx.x * RB;
    const int cbase = blockIdx.y * CHUNK;
    const int t = threadIdx.x;
    const int wid = t >> 6, lane = t & 63;

    {   // stage the 16 x-rows (contiguous 8 KB), float4-coalesced
        const float4* src = (const float4*)(x + (size_t)r0 * DI);
        float4* dst = (float4*)xs;
#pragma unroll
        for (int q = 0; q < (RB * DI / 4) / 256; ++q)
            dst[t + 256 * q] = src[t + 256 * q];
    }
    __syncthreads();

    float acc[RB][4];
#pragma unroll
    for (int r = 0; r < RB; ++r)
#pragma unroll
        for (int s = 0; s < 4; ++s) acc[r][s] = 0.f;

    const float* xTb = xT + cbase + t;
#pragma unroll 4
    for (int d = 0; d < DI; ++d) {
        float xv[4];
#pragma unroll
        for (int s = 0; s < 4; ++s) xv[s] = xTb[(size_t)d * NP2 + 256 * s];
#pragma unroll
        for (int r = 0; r < RB; ++r) {
            const float xr = xs[r * DI + d];            // LDS broadcast (b128 across d)
#pragma unroll
            for (int s = 0; s < 4; ++s) acc[r][s] = fmaf(xr, xv[s], acc[r][s]);
        }
    }

    float sqi[RB], sqj[4];
#pragma unroll
    for (int r = 0; r < RB; ++r) sqi[r] = sq32[r0 + r];
#pragma unroll
    for (int s = 0; s < 4; ++s) sqj[s] = sq32[cbase + t + 256 * s];

    const unsigned long long lml = (1ull << lane) - 1;

#pragma unroll 1
    for (int p = 0; p < 4; ++p) {
        // write fkeys for rows 4p..4p+3
#pragma unroll
        for (int r4 = 0; r4 < 4; ++r4) {
            const int r = 4 * p + r4;
#pragma unroll
            for (int s = 0; s < 4; ++s) {
                const int pos = t + 256 * s;
                const int j = cbase + pos;
                const float dd = sqi[r] + sqj[s] - 2.f * acc[r][s];
                unsigned k = fkey(dd);
                if (j >= NN || j == r0 + r) k = 0xFFFFFFFEu;  // pad + diagonal
                dist4[r4][pos] = k;
            }
        }
        __syncthreads();

        // wave `wid` owns row 4p+wid: 16 values/lane (2-way bank alias = free)
        unsigned kk[16];
#pragma unroll
        for (int u = 0; u < 16; ++u) kk[u] = dist4[wid][lane + 64 * u];

        // bisect to the exact 32nd-smallest key value (32 iters -> window 1)
        unsigned lo = 0u, hi = 0xFFFFFFFFu;
#pragma unroll 1
        for (int it = 0; it < 32; ++it) {
            const unsigned mid = lo + ((hi - lo) >> 1);
            int cnt = 0;
#pragma unroll
            for (int u = 0; u < 16; ++u)
                cnt += (int)__popcll(__ballot(kk[u] <= mid));
            if (cnt >= KNB) hi = mid; else lo = mid;
        }
        const unsigned T = hi;

        // emit all elements <= T (32 + boundary ties <= SLOTS)
        unsigned long long* outp =
            keys + ((size_t)(r0 + 4 * p + wid) * NCHUNK + blockIdx.y) * SLOTS;
        unsigned pref = 0;
#pragma unroll
        for (int u = 0; u < 16; ++u) {
            const unsigned long long b = __ballot(kk[u] <= T);
            const int slot = (int)pref + (int)__popcll(b & lml);
            if ((kk[u] <= T) && slot < SLOTS)
                outp[slot] = ((unsigned long long)kk[u] << 32)
                           | (unsigned)(cbase + lane + 64 * u);
            pref += (unsigned)__popcll(b);
        }
        __syncthreads();   // before next phase overwrites dist4
    }
}

// merge 10 chunk-lists of 48 -> >=64 candidates per row via the same bisection
__global__ void knn_merge_k(const unsigned long long* __restrict__ keys,
                            int* __restrict__ cand)
{
    const int i = blockIdx.x;
    const int lane = threadIdx.x;   // 64 threads
    unsigned long long kk[8];
    unsigned kh[8];
#pragma unroll
    for (int u = 0; u < 8; ++u) {
        const int idx = lane + 64 * u;
        kk[u] = (idx < MTOT) ? keys[(size_t)i * MTOT + idx] : ~0ull;
        kh[u] = (unsigned)(kk[u] >> 32);
    }
    unsigned lo = 0u, hi = 0xFFFFFFFFu;
#pragma unroll 1
    for (int it = 0; it < 32; ++it) {
        const unsigned mid = lo + ((hi - lo) >> 1);
        int cnt = 0;
#pragma unroll
        for (int u = 0; u < 8; ++u)
            cnt += (int)__popcll(__ballot(kh[u] <= mid));
        if (cnt >= 64) hi = mid; else lo = mid;
    }
    const unsigned T = hi;
    const unsigned long long lml = (1ull << lane) - 1;
    unsigned pref = 0;
#pragma unroll
    for (int u = 0; u < 8; ++u) {
        const unsigned long long b = __ballot(kh[u] <= T);
        const int slot = (int)pref + (int)__popcll(b & lml);
        if ((kh[u] <= T) && slot < MCAND)
            cand[(size_t)i * MCAND + slot] = (int)(kk[u] & 0xffffffffu);
        pref += (unsigned)__popcll(b);
    }
}

// exact f64 re-rank of <=128 candidates -> final top-32 in (key,col) order
__global__ void rerank_k(const float* __restrict__ x, const double* __restrict__ sq64,
                         const int* __restrict__ cand, int* __restrict__ nbr)
{
    const int i = blockIdx.x;
    const int lane = threadIdx.x;   // 64
    const int c0 = cand[(size_t)i * MCAND + lane];
    const int c1 = cand[(size_t)i * MCAND + 64 + lane];
    const int s0 = c0 < 0 ? 0 : c0, s1 = c1 < 0 ? 0 : c1;
    const float* xr = x + (size_t)i * DI;     // uniform
    const float* xa = x + (size_t)s0 * DI;
    const float* xb = x + (size_t)s1 * DI;
    double a0 = 0.0, a1 = 0.0;
    for (int d = 0; d < DI; ++d) {
        const double xi = (double)xr[d];
        a0 = fma(xi, (double)xa[d], a0);
        a1 = fma(xi, (double)xb[d], a1);
    }
    const double sqi = sq64[i];
    unsigned long long k0 = ~0ull, k1 = ~0ull;
    if (c0 >= 0) {
        const float dd = (float)(sqi + sq64[s0] - 2.0 * a0);
        k0 = ((unsigned long long)fkey(dd) << 32) | (unsigned)c0;
    }
    if (c1 >= 0) {
        const float dd = (float)(sqi + sq64[s1] - 2.0 * a1);
        k1 = ((unsigned long long)fkey(dd) << 32) | (unsigned)c1;
    }
#pragma unroll 1
    for (int k = 0; k < KNB; ++k) {
        const unsigned long long mym = k0 < k1 ? k0 : k1;
        unsigned long long m = mym;
#pragma unroll
        for (int off = 32; off >= 1; off >>= 1) {
            const unsigned long long o = __shfl_xor(m, off);
            m = o < m ? o : m;
        }
        if (mym == m) {   // unique winner (keys distinct)
            if (k0 == m) k0 = ~0ull; else k1 = ~0ull;
            nbr[(size_t)i * KNB + k] = (int)(m & 0xffffffffu);
        }
    }
}

// attention epilogue: block=row, thread=output dim (DO==256==blockDim)
__global__ __launch_bounds__(256) void gat_k(
    const float* __restrict__ hl, const float* __restrict__ hr,
    const int* __restrict__ nbr, const float* __restrict__ att,
    const float* __restrict__ bias, float* __restrict__ out)
{
    __shared__ int src[NSRC];
    __shared__ float eP[NSRC][4];
    __shared__ float eS[NSRC];
    const int i = blockIdx.x, t = threadIdx.x;
    if (t < KNB) src[t] = nbr[(size_t)i * KNB + t];
    if (t == KNB) src[KNB] = i;   // self-loop appended last, like the reference
    __syncthreads();
    const float at  = att[t];
    const float hrv = hr[(size_t)i * DO + t];
    float hlv[NSRC];
#pragma unroll
    for (int k = 0; k < NSRC; ++k) {
        const float v = hl[(size_t)src[k] * DO + t];
        hlv[k] = v;
        const float z = v + hrv;
        float p = (z > 0.f ? z : NEG * z) * at;
#pragma unroll
        for (int off = 32; off >= 1; off >>= 1) p += __shfl_xor(p, off);
        if ((t & 63) == 0) eP[k][t >> 6] = p;
    }
    __syncthreads();
    if (t < NSRC) eS[t] = eP[t][0] + eP[t][1] + eP[t][2] + eP[t][3];
    __syncthreads();
    float m = eS[0];
#pragma unroll
    for (int k = 1; k < NSRC; ++k) m = fmaxf(m, eS[k]);
    float w[NSRC];
    float ssum = 0.f;
#pragma unroll
    for (int k = 0; k < NSRC; ++k) { w[k] = expf(eS[k] - m); ssum += w[k]; }
    const float inv = 1.f / ssum;
    float o = bias[t];
#pragma unroll
    for (int k = 0; k < NSRC; ++k) o = fmaf(w[k] * inv, hlv[k], o);
    out[(size_t)i * DO + t] = o;
}

extern "C" void kernel_launch(void* const* d_in, const int* in_sizes, int n_in,
                              void* d_out, int out_size, void* d_ws, size_t ws_size,
                              hipStream_t stream) {
    const float* x    = (const float*)d_in[0];
    const float* Wl   = (const float*)d_in[1];
    const float* bl   = (const float*)d_in[2];
    const float* Wr   = (const float*)d_in[3];
    const float* br   = (const float*)d_in[4];
    const float* att  = (const float*)d_in[5];
    const float* bias = (const float*)d_in[6];
    float* out = (float*)d_out;

    char* ws = (char*)d_ws;
    // layout (bytes):
    float*  xT   = (float*)(ws + 0);            //  5,242,880
    double* sq64 = (double*)(ws + 5242880);     //     80,000
    float*  sq32 = (float*)(ws + 5322880);      //     40,960
    float*  hl   = (float*)(ws + 5363840);      // 10,240,000
    float*  hr   = (float*)(ws + 15603840);     // 10,240,000
    unsigned long long* keys = (unsigned long long*)(ws + 25843840); // 38,400,000
    int*    cand = (int*)(ws + 64243840);       //  5,120,000
    int*    nbr  = (int*)(ws + 69363840);       //  1,280,000
    // total ~70.6 MB

    hipMemsetAsync(keys, 0xFF, (size_t)NN * MTOT * 8, stream);
    hipMemsetAsync(cand, 0xFF, (size_t)NN * MCAND * 4, stream);

    transpose32_k<<<dim3(NP2 / 256, DI), 256, 0, stream>>>(x, xT);
    sqrow_k<<<dim3(NP2 / 256), 256, 0, stream>>>(xT, sq64, sq32);
    hgemm_k<<<dim3(NN / RB), 256, 0, stream>>>(x, Wl, bl, Wr, br, hl, hr);
    knn_partial_k<<<dim3(NN / RB, NCHUNK), 256, 0, stream>>>(x, xT, sq32, keys);
    knn_merge_k<<<dim3(NN), 64, 0, stream>>>(keys, cand);
    rerank_k<<<dim3(NN), 64, 0, stream>>>(x, sq64, cand, nbr);
    gat_k<<<dim3(NN), 256, 0, stream>>>(hl, hr, nbr, att, bias, out);
}

// Round 5
// 885.459 us; speedup vs baseline: 2.7968x; 2.7968x over previous
//
#include <hip/hip_runtime.h>

#define NN     10000
#define DI     128
#define DO     256
#define KNB    32
#define NSRC   33      // 32 neighbors + self
#define CHUNK  1024
#define NCHUNK 10      // NP2 / CHUNK
#define RB     16      // rows per block in distance/gemm kernels
#define NP2    10240   // padded column count (multiple of CHUNK)
#define SLOTS  48      // per-(row,chunk) candidate slots (>=32+ties)
#define MTOT   (NCHUNK * SLOTS)   // 480 candidates entering merge
#define MCAND  128     // candidates kept per row for f64 re-rank
#define NEG    0.2f

// monotone map f32 -> u32 preserving < order (handles negatives)
__device__ __forceinline__ unsigned fkey(float f) {
    unsigned u = __float_as_uint(f);
    return (u & 0x80000000u) ? ~u : (u | 0x80000000u);
}

__global__ void transpose32_k(const float* __restrict__ x, float* __restrict__ xT) {
    int j = blockIdx.x * 256 + threadIdx.x;
    int d = blockIdx.y;
    if (j < NP2) xT[(size_t)d * NP2 + j] = (j < NN) ? x[(size_t)j * DI + d] : 0.f;
}

// per-row squared norms in f64 (from coalesced xT), plus f32 copy
__global__ void sqrow_k(const float* __restrict__ xT, double* __restrict__ sq64,
                        float* __restrict__ sq32) {
    int j = blockIdx.x * 256 + threadIdx.x;
    if (j >= NP2) return;
    double s = 0.0;
    for (int d = 0; d < DI; ++d) {
        double v = (double)xT[(size_t)d * NP2 + j];
        s = fma(v, v, s);
    }
    if (j < NN) sq64[j] = s;
    sq32[j] = (j < NN) ? (float)s : 0.f;
}

// h_l = x@W_l + b_l ; h_r = x@W_r + b_r  (f32 vector FMA, 16 rows/block, col=thread)
__global__ __launch_bounds__(256) void hgemm_k(
    const float* __restrict__ x, const float* __restrict__ Wl,
    const float* __restrict__ bl, const float* __restrict__ Wr,
    const float* __restrict__ br, float* __restrict__ hl, float* __restrict__ hr)
{
    const int c = threadIdx.x;
    const int r0 = blockIdx.x * RB;
    float accl[RB], accr[RB];
    const float blv = bl[c], brv = br[c];
#pragma unroll
    for (int r = 0; r < RB; ++r) { accl[r] = blv; accr[r] = brv; }
    for (int d = 0; d < DI; ++d) {
        const float wl = Wl[d * DO + c];
        const float wr = Wr[d * DO + c];
#pragma unroll
        for (int r = 0; r < RB; ++r) {
            const float xv = x[(size_t)(r0 + r) * DI + d];  // wave-uniform
            accl[r] = fmaf(xv, wl, accl[r]);
            accr[r] = fmaf(xv, wr, accr[r]);
        }
    }
#pragma unroll
    for (int r = 0; r < RB; ++r) {
        hl[(size_t)(r0 + r) * DO + c] = accl[r];
        hr[(size_t)(r0 + r) * DO + c] = accr[r];
    }
}

// f32 distances for a 16-row x 1024-col tile; per-row per-chunk top-32 multiset
// via ballot-bisection threshold (exact 32nd-smallest key), emitted with
// ballot-prefix slots. No sorts, no serial pops.
// NOTE: no min-waves bound — acc[16][4] overflow must go to AGPRs (unified
// file), NOT scratch. __launch_bounds__(256,4) caused 7.3 GB of spill traffic.
__global__ __launch_bounds__(256) void knn_partial_k(
    const float* __restrict__ x, const float* __restrict__ xT,
    const float* __restrict__ sq32, unsigned long long* __restrict__ keys)
{
    __shared__ float xs[RB * DI];               // 8 KB
    __shared__ unsigned dist4[4][CHUNK];        // 16 KB (fkey u32)

    const int r0 = blockIdx.x * RB;
    const int cbase = blockIdx.y * CHUNK;
    const int t = threadIdx.x;
    const int wid = t >> 6, lane = t & 63;

    {   // stage the 16 x-rows (contiguous 8 KB), float4-coalesced
        const float4* src = (const float4*)(x + (size_t)r0 * DI);
        float4* dst = (float4*)xs;
#pragma unroll
        for (int q = 0; q < (RB * DI / 4) / 256; ++q)
            dst[t + 256 * q] = src[t + 256 * q];
    }
    __syncthreads();

    float acc[RB][4];
#pragma unroll
    for (int r = 0; r < RB; ++r)
#pragma unroll
        for (int s = 0; s < 4; ++s) acc[r][s] = 0.f;

    const float* xTb = xT + cbase + t;
#pragma unroll 4
    for (int d = 0; d < DI; ++d) {
        float xv[4];
#pragma unroll
        for (int s = 0; s < 4; ++s) xv[s] = xTb[(size_t)d * NP2 + 256 * s];
#pragma unroll
        for (int r = 0; r < RB; ++r) {
            const float xr = xs[r * DI + d];            // LDS broadcast (b128 across d)
#pragma unroll
            for (int s = 0; s < 4; ++s) acc[r][s] = fmaf(xr, xv[s], acc[r][s]);
        }
    }

    float sqi[RB], sqj[4];
#pragma unroll
    for (int r = 0; r < RB; ++r) sqi[r] = sq32[r0 + r];
#pragma unroll
    for (int s = 0; s < 4; ++s) sqj[s] = sq32[cbase + t + 256 * s];

    const unsigned long long lml = (1ull << lane) - 1;

#pragma unroll 1
    for (int p = 0; p < 4; ++p) {
        // write fkeys for rows 4p..4p+3
#pragma unroll
        for (int r4 = 0; r4 < 4; ++r4) {
            const int r = 4 * p + r4;
#pragma unroll
            for (int s = 0; s < 4; ++s) {
                const int pos = t + 256 * s;
                const int j = cbase + pos;
                const float dd = sqi[r] + sqj[s] - 2.f * acc[r][s];
                unsigned k = fkey(dd);
                if (j >= NN || j == r0 + r) k = 0xFFFFFFFEu;  // pad + diagonal
                dist4[r4][pos] = k;
            }
        }
        __syncthreads();

        // wave `wid` owns row 4p+wid: 16 values/lane (2-way bank alias = free)
        unsigned kk[16];
#pragma unroll
        for (int u = 0; u < 16; ++u) kk[u] = dist4[wid][lane + 64 * u];

        // bisect to the exact 32nd-smallest key value (32 iters -> window 1)
        unsigned lo = 0u, hi = 0xFFFFFFFFu;
#pragma unroll 1
        for (int it = 0; it < 32; ++it) {
            const unsigned mid = lo + ((hi - lo) >> 1);
            int cnt = 0;
#pragma unroll
            for (int u = 0; u < 16; ++u)
                cnt += (int)__popcll(__ballot(kk[u] <= mid));
            if (cnt >= KNB) hi = mid; else lo = mid;
        }
        const unsigned T = hi;

        // emit all elements <= T (32 + boundary ties <= SLOTS)
        unsigned long long* outp =
            keys + ((size_t)(r0 + 4 * p + wid) * NCHUNK + blockIdx.y) * SLOTS;
        unsigned pref = 0;
#pragma unroll
        for (int u = 0; u < 16; ++u) {
            const unsigned long long b = __ballot(kk[u] <= T);
            const int slot = (int)pref + (int)__popcll(b & lml);
            if ((kk[u] <= T) && slot < SLOTS)
                outp[slot] = ((unsigned long long)kk[u] << 32)
                           | (unsigned)(cbase + lane + 64 * u);
            pref += (unsigned)__popcll(b);
        }
        __syncthreads();   // before next phase overwrites dist4
    }
}

// merge 10 chunk-lists of 48 -> >=64 candidates per row via the same bisection
__global__ void knn_merge_k(const unsigned long long* __restrict__ keys,
                            int* __restrict__ cand)
{
    const int i = blockIdx.x;
    const int lane = threadIdx.x;   // 64 threads
    unsigned long long kk[8];
    unsigned kh[8];
#pragma unroll
    for (int u = 0; u < 8; ++u) {
        const int idx = lane + 64 * u;
        kk[u] = (idx < MTOT) ? keys[(size_t)i * MTOT + idx] : ~0ull;
        kh[u] = (unsigned)(kk[u] >> 32);
    }
    unsigned lo = 0u, hi = 0xFFFFFFFFu;
#pragma unroll 1
    for (int it = 0; it < 32; ++it) {
        const unsigned mid = lo + ((hi - lo) >> 1);
        int cnt = 0;
#pragma unroll
        for (int u = 0; u < 8; ++u)
            cnt += (int)__popcll(__ballot(kh[u] <= mid));
        if (cnt >= 64) hi = mid; else lo = mid;
    }
    const unsigned T = hi;
    const unsigned long long lml = (1ull << lane) - 1;
    unsigned pref = 0;
#pragma unroll
    for (int u = 0; u < 8; ++u) {
        const unsigned long long b = __ballot(kh[u] <= T);
        const int slot = (int)pref + (int)__popcll(b & lml);
        if ((kh[u] <= T) && slot < MCAND)
            cand[(size_t)i * MCAND + slot] = (int)(kk[u] & 0xffffffffu);
        pref += (unsigned)__popcll(b);
    }
}

// exact f64 re-rank of <=128 candidates -> final top-32 in (key,col) order
__global__ void rerank_k(const float* __restrict__ x, const double* __restrict__ sq64,
                         const int* __restrict__ cand, int* __restrict__ nbr)
{
    const int i = blockIdx.x;
    const int lane = threadIdx.x;   // 64
    const int c0 = cand[(size_t)i * MCAND + lane];
    const int c1 = cand[(size_t)i * MCAND + 64 + lane];
    const int s0 = c0 < 0 ? 0 : c0, s1 = c1 < 0 ? 0 : c1;
    const float* xr = x + (size_t)i * DI;     // uniform
    const float* xa = x + (size_t)s0 * DI;
    const float* xb = x + (size_t)s1 * DI;
    double a0 = 0.0, a1 = 0.0;
    for (int d = 0; d < DI; ++d) {
        const double xi = (double)xr[d];
        a0 = fma(xi, (double)xa[d], a0);
        a1 = fma(xi, (double)xb[d], a1);
    }
    const double sqi = sq64[i];
    unsigned long long k0 = ~0ull, k1 = ~0ull;
    if (c0 >= 0) {
        const float dd = (float)(sqi + sq64[s0] - 2.0 * a0);
        k0 = ((unsigned long long)fkey(dd) << 32) | (unsigned)c0;
    }
    if (c1 >= 0) {
        const float dd = (float)(sqi + sq64[s1] - 2.0 * a1);
        k1 = ((unsigned long long)fkey(dd) << 32) | (unsigned)c1;
    }
#pragma unroll 1
    for (int k = 0; k < KNB; ++k) {
        const unsigned long long mym = k0 < k1 ? k0 : k1;
        unsigned long long m = mym;
#pragma unroll
        for (int off = 32; off >= 1; off >>= 1) {
            const unsigned long long o = __shfl_xor(m, off);
            m = o < m ? o : m;
        }
        if (mym == m) {   // unique winner (keys distinct)
            if (k0 == m) k0 = ~0ull; else k1 = ~0ull;
            nbr[(size_t)i * KNB + k] = (int)(m & 0xffffffffu);
        }
    }
}

// attention epilogue: block=row, thread=output dim (DO==256==blockDim)
__global__ __launch_bounds__(256) void gat_k(
    const float* __restrict__ hl, const float* __restrict__ hr,
    const int* __restrict__ nbr, const float* __restrict__ att,
    const float* __restrict__ bias, float* __restrict__ out)
{
    __shared__ int src[NSRC];
    __shared__ float eP[NSRC][4];
    __shared__ float eS[NSRC];
    const int i = blockIdx.x, t = threadIdx.x;
    if (t < KNB) src[t] = nbr[(size_t)i * KNB + t];
    if (t == KNB) src[KNB] = i;   // self-loop appended last, like the reference
    __syncthreads();
    const float at  = att[t];
    const float hrv = hr[(size_t)i * DO + t];
    float hlv[NSRC];
#pragma unroll
    for (int k = 0; k < NSRC; ++k) {
        const float v = hl[(size_t)src[k] * DO + t];
        hlv[k] = v;
        const float z = v + hrv;
        float p = (z > 0.f ? z : NEG * z) * at;
#pragma unroll
        for (int off = 32; off >= 1; off >>= 1) p += __shfl_xor(p, off);
        if ((t & 63) == 0) eP[k][t >> 6] = p;
    }
    __syncthreads();
    if (t < NSRC) eS[t] = eP[t][0] + eP[t][1] + eP[t][2] + eP[t][3];
    __syncthreads();
    float m = eS[0];
#pragma unroll
    for (int k = 1; k < NSRC; ++k) m = fmaxf(m, eS[k]);
    float w[NSRC];
    float ssum = 0.f;
#pragma unroll
    for (int k = 0; k < NSRC; ++k) { w[k] = expf(eS[k] - m); ssum += w[k]; }
    const float inv = 1.f / ssum;
    float o = bias[t];
#pragma unroll
    for (int k = 0; k < NSRC; ++k) o = fmaf(w[k] * inv, hlv[k], o);
    out[(size_t)i * DO + t] = o;
}

extern "C" void kernel_launch(void* const* d_in, const int* in_sizes, int n_in,
                              void* d_out, int out_size, void* d_ws, size_t ws_size,
                              hipStream_t stream) {
    const float* x    = (const float*)d_in[0];
    const float* Wl   = (const float*)d_in[1];
    const float* bl   = (const float*)d_in[2];
    const float* Wr   = (const float*)d_in[3];
    const float* br   = (const float*)d_in[4];
    const float* att  = (const float*)d_in[5];
    const float* bias = (const float*)d_in[6];
    float* out = (float*)d_out;

    char* ws = (char*)d_ws;
    // layout (bytes):
    float*  xT   = (float*)(ws + 0);            //  5,242,880
    double* sq64 = (double*)(ws + 5242880);     //     80,000
    float*  sq32 = (float*)(ws + 5322880);      //     40,960
    float*  hl   = (float*)(ws + 5363840);      // 10,240,000
    float*  hr   = (float*)(ws + 15603840);     // 10,240,000
    unsigned long long* keys = (unsigned long long*)(ws + 25843840); // 38,400,000
    int*    cand = (int*)(ws + 64243840);       //  5,120,000
    int*    nbr  = (int*)(ws + 69363840);       //  1,280,000
    // total ~70.6 MB

    hipMemsetAsync(keys, 0xFF, (size_t)NN * MTOT * 8, stream);
    hipMemsetAsync(cand, 0xFF, (size_t)NN * MCAND * 4, stream);

    transpose32_k<<<dim3(NP2 / 256, DI), 256, 0, stream>>>(x, xT);
    sqrow_k<<<dim3(NP2 / 256), 256, 0, stream>>>(xT, sq64, sq32);
    hgemm_k<<<dim3(NN / RB), 256, 0, stream>>>(x, Wl, bl, Wr, br, hl, hr);
    knn_partial_k<<<dim3(NN / RB, NCHUNK), 256, 0, stream>>>(x, xT, sq32, keys);
    knn_merge_k<<<dim3(NN), 64, 0, stream>>>(keys, cand);
    rerank_k<<<dim3(NN), 64, 0, stream>>>(x, sq64, cand, nbr);
    gat_k<<<dim3(NN), 256, 0, stream>>>(hl, hr, nbr, att, bias, out);
}

// Round 6
// 772.369 us; speedup vs baseline: 3.2063x; 1.1464x over previous
//
#include <hip/hip_runtime.h>

#define NN     10000
#define DI     128
#define DO     256
#define KNB    32
#define NSRC   33      // 32 neighbors + self
#define CHUNK  512
#define NCHUNK 20      // NP2 / CHUNK
#define RB     16      // rows per block in distance/gemm kernels
#define NP2    10240   // padded column count (multiple of CHUNK)
#define MTOT   (NCHUNK * KNB)     // 640 candidates entering merge
#define MCAND  128     // candidates kept per row for f64 re-rank
#define NEG    0.2f

// monotone map f32 -> u32 preserving < order (handles negatives)
__device__ __forceinline__ unsigned fkey(float f) {
    unsigned u = __float_as_uint(f);
    return (u & 0x80000000u) ? ~u : (u | 0x80000000u);
}

__global__ void transpose32_k(const float* __restrict__ x, float* __restrict__ xT) {
    int j = blockIdx.x * 256 + threadIdx.x;
    int d = blockIdx.y;
    if (j < NP2) xT[(size_t)d * NP2 + j] = (j < NN) ? x[(size_t)j * DI + d] : 0.f;
}

// per-row squared norms in f64 (from coalesced xT), plus f32 copy
__global__ void sqrow_k(const float* __restrict__ xT, double* __restrict__ sq64,
                        float* __restrict__ sq32) {
    int j = blockIdx.x * 256 + threadIdx.x;
    if (j >= NP2) return;
    double s = 0.0;
    for (int d = 0; d < DI; ++d) {
        double v = (double)xT[(size_t)d * NP2 + j];
        s = fma(v, v, s);
    }
    if (j < NN) sq64[j] = s;
    sq32[j] = (j < NN) ? (float)s : 0.f;
}

// h_l = x@W_l + b_l ; h_r = x@W_r + b_r  (f32 vector FMA, 16 rows/block, col=thread)
__global__ __launch_bounds__(256) void hgemm_k(
    const float* __restrict__ x, const float* __restrict__ Wl,
    const float* __restrict__ bl, const float* __restrict__ Wr,
    const float* __restrict__ br, float* __restrict__ hl, float* __restrict__ hr)
{
    const int c = threadIdx.x;
    const int r0 = blockIdx.x * RB;
    float accl[RB], accr[RB];
    const float blv = bl[c], brv = br[c];
#pragma unroll
    for (int r = 0; r < RB; ++r) { accl[r] = blv; accr[r] = brv; }
    for (int d = 0; d < DI; ++d) {
        const float wl = Wl[d * DO + c];
        const float wr = Wr[d * DO + c];
#pragma unroll
        for (int r = 0; r < RB; ++r) {
            const float xv = x[(size_t)(r0 + r) * DI + d];  // wave-uniform
            accl[r] = fmaf(xv, wl, accl[r]);
            accr[r] = fmaf(xv, wr, accr[r]);
        }
    }
#pragma unroll
    for (int r = 0; r < RB; ++r) {
        hl[(size_t)(r0 + r) * DO + c] = accl[r];
        hr[(size_t)(r0 + r) * DO + c] = accr[r];
    }
}

// f32 distances for a 16-row x 512-col tile; exact per-(row,chunk) top-32 by
// (key,col) via ballot-bisection threshold + two-pass (<T, ==T) emission.
// acc[16][2]=32 regs dies in the single fkey-write phase -> no spill.
__global__ __launch_bounds__(256) void knn_partial_k(
    const float* __restrict__ x, const float* __restrict__ xT,
    const float* __restrict__ sq32, unsigned long long* __restrict__ keys)
{
    __shared__ float xs[RB * DI];              // 8 KB
    __shared__ unsigned dist[RB][CHUNK];       // 32 KB (fkey u32), all 16 rows

    const int r0 = blockIdx.x * RB;
    const int cbase = blockIdx.y * CHUNK;
    const int t = threadIdx.x;
    const int wid = t >> 6, lane = t & 63;

    {   // stage the 16 x-rows (contiguous 8 KB), float4-coalesced
        const float4* src = (const float4*)(x + (size_t)r0 * DI);
        float4* dst = (float4*)xs;
#pragma unroll
        for (int q = 0; q < (RB * DI / 4) / 256; ++q)
            dst[t + 256 * q] = src[t + 256 * q];
    }
    __syncthreads();

    // thread owns two ADJACENT cols (2t, 2t+1) -> float2 global loads
    float acc[RB][2];
#pragma unroll
    for (int r = 0; r < RB; ++r) { acc[r][0] = 0.f; acc[r][1] = 0.f; }

    const float* xTb = xT + cbase + 2 * t;
#pragma unroll 4
    for (int d = 0; d < DI; ++d) {
        const float2 xv = *(const float2*)(xTb + (size_t)d * NP2);
#pragma unroll
        for (int r = 0; r < RB; ++r) {
            const float xr = xs[r * DI + d];            // LDS broadcast (b128 across d)
            acc[r][0] = fmaf(xr, xv.x, acc[r][0]);
            acc[r][1] = fmaf(xr, xv.y, acc[r][1]);
        }
    }

    // fkey write for ALL 16 rows at once; acc dies here
    const float2 sqj = *(const float2*)(sq32 + cbase + 2 * t);
#pragma unroll
    for (int r = 0; r < RB; ++r) {
        const float sqi = sq32[r0 + r];
        const int j0 = cbase + 2 * t;
        unsigned k0 = fkey(sqi + sqj.x - 2.f * acc[r][0]);
        unsigned k1 = fkey(sqi + sqj.y - 2.f * acc[r][1]);
        if (j0     >= NN || j0     == r0 + r) k0 = 0xFFFFFFFEu;
        if (j0 + 1 >= NN || j0 + 1 == r0 + r) k1 = 0xFFFFFFFEu;
        *(uint2*)&dist[r][2 * t] = make_uint2(k0, k1);
    }
    __syncthreads();

    const unsigned long long lml = (1ull << lane) - 1;

    // wave `wid` selects rows wid*4..wid*4+3
#pragma unroll 1
    for (int rr = 0; rr < 4; ++rr) {
        const int r = wid * 4 + rr;
        unsigned kk[8];
#pragma unroll
        for (int u = 0; u < 8; ++u) kk[u] = dist[r][lane + 64 * u];

        // bisect to the exact 32nd-smallest key (32 iters -> window 1)
        unsigned lo = 0u, hi = 0xFFFFFFFFu;
#pragma unroll 1
        for (int it = 0; it < 32; ++it) {
            const unsigned mid = lo + ((hi - lo) >> 1);
            int cnt = 0;
#pragma unroll
            for (int u = 0; u < 8; ++u)
                cnt += (int)__popcll(__ballot(kk[u] <= mid));
            if (cnt >= KNB) hi = mid; else lo = mid;
        }
        const unsigned T = hi;

        unsigned long long* outp =
            keys + ((size_t)(r0 + r) * NCHUNK + blockIdx.y) * KNB;
        // pass 1: strictly < T (count <= 31)
        unsigned pref = 0;
#pragma unroll
        for (int u = 0; u < 8; ++u) {
            const unsigned long long b = __ballot(kk[u] < T);
            const int slot = (int)pref + (int)__popcll(b & lml);
            if (kk[u] < T)
                outp[slot] = ((unsigned long long)kk[u] << 32)
                           | (unsigned)(cbase + lane + 64 * u);
            pref += (unsigned)__popcll(b);
        }
        // pass 2: == T ties, in col order, fill up to exactly 32
#pragma unroll
        for (int u = 0; u < 8; ++u) {
            const unsigned long long b = __ballot(kk[u] == T);
            const int slot = (int)pref + (int)__popcll(b & lml);
            if (kk[u] == T && slot < KNB)
                outp[slot] = ((unsigned long long)kk[u] << 32)
                           | (unsigned)(cbase + lane + 64 * u);
            pref += (unsigned)__popcll(b);
        }
    }
}

// merge 20 chunk-lists of 32 -> >=64 candidates per row via bisection on f32 key
__global__ void knn_merge_k(const unsigned long long* __restrict__ keys,
                            int* __restrict__ cand)
{
    const int i = blockIdx.x;
    const int lane = threadIdx.x;   // 64 threads
    unsigned long long kk[MTOT / 64];   // 10
    unsigned kh[MTOT / 64];
#pragma unroll
    for (int u = 0; u < MTOT / 64; ++u) {
        kk[u] = keys[(size_t)i * MTOT + lane + 64 * u];
        kh[u] = (unsigned)(kk[u] >> 32);
    }
    unsigned lo = 0u, hi = 0xFFFFFFFFu;
#pragma unroll 1
    for (int it = 0; it < 32; ++it) {
        const unsigned mid = lo + ((hi - lo) >> 1);
        int cnt = 0;
#pragma unroll
        for (int u = 0; u < MTOT / 64; ++u)
            cnt += (int)__popcll(__ballot(kh[u] <= mid));
        if (cnt >= 64) hi = mid; else lo = mid;
    }
    const unsigned T = hi;
    const unsigned long long lml = (1ull << lane) - 1;
    unsigned pref = 0;
#pragma unroll
    for (int u = 0; u < MTOT / 64; ++u) {
        const unsigned long long b = __ballot(kh[u] <= T);
        const int slot = (int)pref + (int)__popcll(b & lml);
        if ((kh[u] <= T) && slot < MCAND)
            cand[(size_t)i * MCAND + slot] = (int)(kk[u] & 0xffffffffu);
        pref += (unsigned)__popcll(b);
    }
}

// exact f64 re-rank of <=128 candidates -> final top-32 in (key,col) order
__global__ void rerank_k(const float* __restrict__ x, const double* __restrict__ sq64,
                         const int* __restrict__ cand, int* __restrict__ nbr)
{
    const int i = blockIdx.x;
    const int lane = threadIdx.x;   // 64
    const int c0 = cand[(size_t)i * MCAND + lane];
    const int c1 = cand[(size_t)i * MCAND + 64 + lane];
    const int s0 = c0 < 0 ? 0 : c0, s1 = c1 < 0 ? 0 : c1;
    const float* xr = x + (size_t)i * DI;     // uniform
    const float* xa = x + (size_t)s0 * DI;
    const float* xb = x + (size_t)s1 * DI;
    double a0 = 0.0, a1 = 0.0;
    for (int d = 0; d < DI; ++d) {
        const double xi = (double)xr[d];
        a0 = fma(xi, (double)xa[d], a0);
        a1 = fma(xi, (double)xb[d], a1);
    }
    const double sqi = sq64[i];
    unsigned long long k0 = ~0ull, k1 = ~0ull;
    if (c0 >= 0) {
        const float dd = (float)(sqi + sq64[s0] - 2.0 * a0);
        k0 = ((unsigned long long)fkey(dd) << 32) | (unsigned)c0;
    }
    if (c1 >= 0) {
        const float dd = (float)(sqi + sq64[s1] - 2.0 * a1);
        k1 = ((unsigned long long)fkey(dd) << 32) | (unsigned)c1;
    }
#pragma unroll 1
    for (int k = 0; k < KNB; ++k) {
        const unsigned long long mym = k0 < k1 ? k0 : k1;
        unsigned long long m = mym;
#pragma unroll
        for (int off = 32; off >= 1; off >>= 1) {
            const unsigned long long o = __shfl_xor(m, off);
            m = o < m ? o : m;
        }
        if (mym == m) {   // unique winner (keys distinct)
            if (k0 == m) k0 = ~0ull; else k1 = ~0ull;
            nbr[(size_t)i * KNB + k] = (int)(m & 0xffffffffu);
        }
    }
}

// attention epilogue: block=row, thread=output dim (DO==256==blockDim)
__global__ __launch_bounds__(256) void gat_k(
    const float* __restrict__ hl, const float* __restrict__ hr,
    const int* __restrict__ nbr, const float* __restrict__ att,
    const float* __restrict__ bias, float* __restrict__ out)
{
    __shared__ int src[NSRC];
    __shared__ float eP[NSRC][4];
    __shared__ float eS[NSRC];
    const int i = blockIdx.x, t = threadIdx.x;
    if (t < KNB) src[t] = nbr[(size_t)i * KNB + t];
    if (t == KNB) src[KNB] = i;   // self-loop appended last, like the reference
    __syncthreads();
    const float at  = att[t];
    const float hrv = hr[(size_t)i * DO + t];
    float hlv[NSRC];
#pragma unroll
    for (int k = 0; k < NSRC; ++k) {
        const float v = hl[(size_t)src[k] * DO + t];
        hlv[k] = v;
        const float z = v + hrv;
        float p = (z > 0.f ? z : NEG * z) * at;
#pragma unroll
        for (int off = 32; off >= 1; off >>= 1) p += __shfl_xor(p, off);
        if ((t & 63) == 0) eP[k][t >> 6] = p;
    }
    __syncthreads();
    if (t < NSRC) eS[t] = eP[t][0] + eP[t][1] + eP[t][2] + eP[t][3];
    __syncthreads();
    float m = eS[0];
#pragma unroll
    for (int k = 1; k < NSRC; ++k) m = fmaxf(m, eS[k]);
    float w[NSRC];
    float ssum = 0.f;
#pragma unroll
    for (int k = 0; k < NSRC; ++k) { w[k] = expf(eS[k] - m); ssum += w[k]; }
    const float inv = 1.f / ssum;
    float o = bias[t];
#pragma unroll
    for (int k = 0; k < NSRC; ++k) o = fmaf(w[k] * inv, hlv[k], o);
    out[(size_t)i * DO + t] = o;
}

extern "C" void kernel_launch(void* const* d_in, const int* in_sizes, int n_in,
                              void* d_out, int out_size, void* d_ws, size_t ws_size,
                              hipStream_t stream) {
    const float* x    = (const float*)d_in[0];
    const float* Wl   = (const float*)d_in[1];
    const float* bl   = (const float*)d_in[2];
    const float* Wr   = (const float*)d_in[3];
    const float* br   = (const float*)d_in[4];
    const float* att  = (const float*)d_in[5];
    const float* bias = (const float*)d_in[6];
    float* out = (float*)d_out;

    char* ws = (char*)d_ws;
    // layout (bytes) — hl/hr alias the keys region: the kNN pipeline
    // (knn_partial -> merge -> rerank) fully consumes keys/cand BEFORE
    // hgemm_k writes hl/hr over them (stream-ordered).
    float*  xT   = (float*)(ws + 0);            //  5,242,880
    double* sq64 = (double*)(ws + 5242880);     //     80,000
    float*  sq32 = (float*)(ws + 5322880);      //     40,960
    int*    nbr  = (int*)(ws + 5363840);        //  1,280,000
    int*    cand = (int*)(ws + 6643840);        //  5,120,000
    unsigned long long* keys = (unsigned long long*)(ws + 11763840); // 51,200,000
    float*  hl   = (float*)(ws + 11763840);     // 10,240,000 (aliases keys)
    float*  hr   = (float*)(ws + 22003840);     // 10,240,000 (aliases keys)
    // total = 62,963,840 bytes (~63 MB)

    hipMemsetAsync(cand, 0xFF, (size_t)NN * MCAND * 4, stream);

    transpose32_k<<<dim3(NP2 / 256, DI), 256, 0, stream>>>(x, xT);
    sqrow_k<<<dim3(NP2 / 256), 256, 0, stream>>>(xT, sq64, sq32);
    knn_partial_k<<<dim3(NN / RB, NCHUNK), 256, 0, stream>>>(x, xT, sq32, keys);
    knn_merge_k<<<dim3(NN), 64, 0, stream>>>(keys, cand);
    rerank_k<<<dim3(NN), 64, 0, stream>>>(x, sq64, cand, nbr);
    hgemm_k<<<dim3(NN / RB), 256, 0, stream>>>(x, Wl, bl, Wr, br, hl, hr);
    gat_k<<<dim3(NN), 256, 0, stream>>>(hl, hr, nbr, att, bias, out);
}

// Round 7
// 559.958 us; speedup vs baseline: 4.4225x; 1.3793x over previous
//
#include <hip/hip_runtime.h>

#define NN     10000
#define DI     128
#define DO     256
#define KNB    32
#define NSRC   33      // 32 neighbors + self
#define CHUNK  512
#define NCHUNK 20      // NP2 / CHUNK
#define RB     16      // rows per tile
#define NP2    10240   // padded column count
#define SLOTS  48      // per-(row,chunk) candidate slots (32 + ties)
#define MTOT   (NCHUNK * SLOTS)   // 960
#define MCAND  64      // exact candidate count entering f64 re-rank
#define NEG    0.2f

typedef __attribute__((ext_vector_type(8))) short bf16x8;
typedef __attribute__((ext_vector_type(4))) float f32x4;

// monotone map f32 -> u32 preserving < order (handles negatives)
__device__ __forceinline__ unsigned fkey(float f) {
    unsigned u = __float_as_uint(f);
    return (u & 0x80000000u) ? ~u : (u | 0x80000000u);
}

__device__ __forceinline__ unsigned short bf16rne(float f) {
    unsigned u = __float_as_uint(f);
    unsigned r = u + 0x7FFFu + ((u >> 16) & 1u);
    return (unsigned short)(r >> 16);
}

// B-operand prep: split x cols into bf16 hi/lo planes, MFMA-B-fragment-linear:
// element (k, col): ct=col>>4, lane=((k>>3)&3)*16+(col&15), ks=k>>5, j=k&7
// idx = ((ct*4+ks)*64+lane)*8+j  -> hot-kernel loads are dwordx4/lane.
__global__ void bsplit_k(const float* __restrict__ x,
                         unsigned short* __restrict__ Bhi,
                         unsigned short* __restrict__ Blo) {
    const int t = threadIdx.x;
    const int col = blockIdx.x * 2 + (t >> 7);
    const int k = t & 127;
    const float v = (col < NN) ? x[(size_t)col * DI + k] : 0.f;
    const unsigned short hb = bf16rne(v);
    const float hf = __uint_as_float((unsigned)hb << 16);
    const unsigned short lb = bf16rne(v - hf);
    const int ct = col >> 4, lr = col & 15;
    const int ks = k >> 5, hi4 = (k >> 3) & 3, j = k & 7;
    const int lane = hi4 * 16 + lr;
    const size_t idx = ((size_t)(ct * 4 + ks) * 64 + lane) * 8 + j;
    Bhi[idx] = hb;
    Blo[idx] = lb;
}

// A-operand prep: same fragment mapping over rows; hi/lo planes interleaved
// per (rt,ks) with plane stride 512 shorts.
__global__ void asplit_k(const float* __restrict__ x,
                         unsigned short* __restrict__ aF) {
    const int t = threadIdx.x;
    const int row = blockIdx.x * 2 + (t >> 7);
    const int k = t & 127;
    const float v = x[(size_t)row * DI + k];
    const unsigned short hb = bf16rne(v);
    const float hf = __uint_as_float((unsigned)hb << 16);
    const unsigned short lb = bf16rne(v - hf);
    const int rt = row >> 4, lr = row & 15;
    const int ks = k >> 5, hi4 = (k >> 3) & 3, j = k & 7;
    const int lane = hi4 * 16 + lr;
    const size_t idx = (((size_t)(rt * 4 + ks) * 2) * 64 + lane) * 8 + j;
    aF[idx] = hb;
    aF[idx + 512] = lb;
}

// per-row squared norms: f64 exact + f32 copy (16 rows/block, staged via LDS)
__global__ __launch_bounds__(256) void sqrow_k(const float* __restrict__ x,
                                               double* __restrict__ sq64,
                                               float* __restrict__ sq32) {
    __shared__ float xs[RB * DI];
    const int t = threadIdx.x;
    const int r0 = blockIdx.x * RB;
    if (r0 >= NN) {                    // pad rows
        if (t < RB) sq32[r0 + t] = 0.f;
        return;
    }
    {
        const float4* src = (const float4*)(x + (size_t)r0 * DI);
        float4* dst = (float4*)xs;
#pragma unroll
        for (int q = 0; q < (RB * DI / 4) / 256; ++q)
            dst[t + 256 * q] = src[t + 256 * q];
    }
    __syncthreads();
    const int row = t >> 4, sub = t & 15;
    double s = 0.0;
#pragma unroll
    for (int q = 0; q < 8; ++q) {
        const float v = xs[row * DI + sub * 8 + q];
        s = fma((double)v, (double)v, s);
    }
#pragma unroll
    for (int off = 8; off >= 1; off >>= 1) s += __shfl_xor(s, off);
    if (sub == 0) { sq64[r0 + row] = s; sq32[r0 + row] = (float)s; }
}

// h_l = x@W_l + b_l ; h_r = x@W_r + b_r  (f32 vector FMA)
__global__ __launch_bounds__(256) void hgemm_k(
    const float* __restrict__ x, const float* __restrict__ Wl,
    const float* __restrict__ bl, const float* __restrict__ Wr,
    const float* __restrict__ br, float* __restrict__ hl, float* __restrict__ hr)
{
    const int c = threadIdx.x;
    const int r0 = blockIdx.x * RB;
    float accl[RB], accr[RB];
    const float blv = bl[c], brv = br[c];
#pragma unroll
    for (int r = 0; r < RB; ++r) { accl[r] = blv; accr[r] = brv; }
    for (int d = 0; d < DI; ++d) {
        const float wl = Wl[d * DO + c];
        const float wr = Wr[d * DO + c];
#pragma unroll
        for (int r = 0; r < RB; ++r) {
            const float xv = x[(size_t)(r0 + r) * DI + d];  // wave-uniform
            accl[r] = fmaf(xv, wl, accl[r]);
            accr[r] = fmaf(xv, wr, accr[r]);
        }
    }
#pragma unroll
    for (int r = 0; r < RB; ++r) {
        hl[(size_t)(r0 + r) * DO + c] = accl[r];
        hr[(size_t)(r0 + r) * DO + c] = accr[r];
    }
}

// MFMA split-bf16 distance pass: 16 rows x 512 cols per block.
// Wave w covers cols [w*128, w*128+128) as 8 col-tiles; per tile 12 MFMAs
// (4 k-steps x {Ah*Bh, Ah*Bl, Al*Bh}). u16 fkeys -> LDS -> ballot-bisection
// top-32 superset per (row, chunk); chunk lists self-padded to SLOTS.
__global__ __launch_bounds__(256) void knn_partial_k(
    const unsigned short* __restrict__ aF, const unsigned short* __restrict__ Bhi,
    const unsigned short* __restrict__ Blo, const float* __restrict__ sq32,
    unsigned* __restrict__ keys)
{
    __shared__ unsigned short dist16[RB][CHUNK];   // 16 KB
    const int rt = blockIdx.x;
    const int r0 = rt * RB;
    const int cbase = blockIdx.y * CHUNK;
    const int t = threadIdx.x;
    const int wid = t >> 6, lane = t & 63;
    const int wbase = wid * 128;

    // A fragments (16 rows x 128 k, hi+lo): 8 x dwordx4 per lane
    bf16x8 ah[4], al[4];
#pragma unroll
    for (int ks = 0; ks < 4; ++ks) {
        const size_t ab = ((size_t)(rt * 4 + ks) * 2) * 512 + (size_t)lane * 8;
        ah[ks] = *(const bf16x8*)(aF + ab);
        al[ks] = *(const bf16x8*)(aF + ab + 512);
    }
    const int rgrp = (lane >> 4) * 4;
    float sqiv[4], sqjv[8];
#pragma unroll
    for (int rg = 0; rg < 4; ++rg) sqiv[rg] = sq32[r0 + rgrp + rg];
#pragma unroll
    for (int ct = 0; ct < 8; ++ct)
        sqjv[ct] = sq32[cbase + wbase + ct * 16 + (lane & 15)];

#pragma unroll 1
    for (int ct = 0; ct < 8; ++ct) {
        const int ctg = (cbase >> 4) + wid * 8 + ct;
        bf16x8 bh[4], bl_[4];
#pragma unroll
        for (int ks = 0; ks < 4; ++ks) {
            const size_t bb = ((size_t)(ctg * 4 + ks)) * 512 + (size_t)lane * 8;
            bh[ks]  = *(const bf16x8*)(Bhi + bb);
            bl_[ks] = *(const bf16x8*)(Blo + bb);
        }
        f32x4 acc = {0.f, 0.f, 0.f, 0.f};
#pragma unroll
        for (int ks = 0; ks < 4; ++ks) {
            acc = __builtin_amdgcn_mfma_f32_16x16x32_bf16(ah[ks], bh[ks],  acc, 0, 0, 0);
            acc = __builtin_amdgcn_mfma_f32_16x16x32_bf16(ah[ks], bl_[ks], acc, 0, 0, 0);
            acc = __builtin_amdgcn_mfma_f32_16x16x32_bf16(al[ks], bh[ks],  acc, 0, 0, 0);
        }
        const int col_l = wbase + ct * 16 + (lane & 15);
        const int col_g = cbase + col_l;
        const float sqj = sqjv[ct];
#pragma unroll
        for (int rg = 0; rg < 4; ++rg) {   // C/D: col=lane&15, row=(lane>>4)*4+rg
            const int row = rgrp + rg;
            const float dd = sqiv[rg] + sqj - 2.f * acc[rg];
            unsigned k16 = fkey(dd) >> 16;
            if (col_g >= NN || col_g == r0 + row) k16 = 0xFFFEu;  // pad + diagonal
            dist16[row][col_l] = (unsigned short)k16;
        }
    }
    __syncthreads();

    const unsigned long long lml = (1ull << lane) - 1;
#pragma unroll 1
    for (int rr = 0; rr < 4; ++rr) {
        const int r = wid * 4 + rr;
        unsigned kk[8];
#pragma unroll
        for (int u = 0; u < 8; ++u) kk[u] = dist16[r][lane + 64 * u];

        // 16-iter bisect to the exact 32nd-smallest u16 key
        unsigned lo = 0, hi = 0xFFFFu;
#pragma unroll 1
        for (int it = 0; it < 16; ++it) {
            const unsigned mid = (lo + hi) >> 1;
            int cnt = 0;
#pragma unroll
            for (int u = 0; u < 8; ++u)
                cnt += (int)__popcll(__ballot(kk[u] <= mid));
            if (cnt >= KNB) hi = mid; else lo = mid;
        }
        const unsigned T = hi;

        unsigned* outp = keys + ((size_t)(r0 + r) * NCHUNK + blockIdx.y) * SLOTS;
        unsigned pref = 0;
#pragma unroll
        for (int u = 0; u < 8; ++u) {       // strictly < T  (<= 31 of them)
            const unsigned long long b = __ballot(kk[u] < T);
            const int slot = (int)pref + (int)__popcll(b & lml);
            if (kk[u] < T)
                outp[slot] = (kk[u] << 16) | (unsigned)(cbase + lane + 64 * u);
            pref += (unsigned)__popcll(b);
        }
#pragma unroll
        for (int u = 0; u < 8; ++u) {       // == T ties, col order, capped
            const unsigned long long b = __ballot(kk[u] == T);
            const int slot = (int)pref + (int)__popcll(b & lml);
            if (kk[u] == T && slot < SLOTS)
                outp[slot] = (kk[u] << 16) | (unsigned)(cbase + lane + 64 * u);
            pref += (unsigned)__popcll(b);
        }
        if (lane < SLOTS && lane >= (int)pref)   // self-pad unused slots
            outp[lane] = 0xFFFFFFFFu;
    }
}

// merge 20 chunk-lists of 48 -> exactly 64 candidates per row (packed keys
// (key16<<16)|col are distinct, so bisection threshold emits exactly 64)
__global__ void knn_merge_k(const unsigned* __restrict__ keys,
                            int* __restrict__ cand)
{
    const int i = blockIdx.x;
    const int lane = threadIdx.x;   // 64
    unsigned kk[MTOT / 64];         // 15
#pragma unroll
    for (int u = 0; u < MTOT / 64; ++u)
        kk[u] = keys[(size_t)i * MTOT + lane + 64 * u];
    unsigned lo = 0, hi = 0xFFFFFFFFu;
#pragma unroll 1
    for (int it = 0; it < 32; ++it) {
        const unsigned mid = lo + ((hi - lo) >> 1);
        int cnt = 0;
#pragma unroll
        for (int u = 0; u < MTOT / 64; ++u)
            cnt += (int)__popcll(__ballot(kk[u] <= mid));
        if (cnt >= MCAND) hi = mid; else lo = mid;
    }
    const unsigned T = hi;
    const unsigned long long lml = (1ull << lane) - 1;
    unsigned pref = 0;
#pragma unroll
    for (int u = 0; u < MTOT / 64; ++u) {
        const unsigned long long b = __ballot(kk[u] <= T);
        const int slot = (int)pref + (int)__popcll(b & lml);
        if (kk[u] <= T)
            cand[(size_t)i * MCAND + slot] = (int)(kk[u] & 0xFFFFu);
        pref += (unsigned)__popcll(b);
    }
}

// exact f64 re-rank of exactly 64 candidates -> final top-32 in (key,col) order
__global__ void rerank_k(const float* __restrict__ x, const double* __restrict__ sq64,
                         const int* __restrict__ cand, int* __restrict__ nbr)
{
    const int i = blockIdx.x;
    const int lane = threadIdx.x;   // 64
    const int c = cand[(size_t)i * MCAND + lane];
    const float* xr = x + (size_t)i * DI;     // uniform
    const float* xc = x + (size_t)c * DI;
    double a = 0.0;
#pragma unroll 4
    for (int d = 0; d < DI; ++d)
        a = fma((double)xr[d], (double)xc[d], a);
    const float dd = (float)(sq64[i] + sq64[c] - 2.0 * a);
    unsigned long long key = ((unsigned long long)fkey(dd) << 32) | (unsigned)c;
#pragma unroll 1
    for (int k = 0; k < KNB; ++k) {
        unsigned long long m = key;
#pragma unroll
        for (int off = 32; off >= 1; off >>= 1) {
            const unsigned long long o = __shfl_xor(m, off);
            m = o < m ? o : m;
        }
        if (key == m) { key = ~0ull; nbr[(size_t)i * KNB + k] = (int)(m & 0xffffffffu); }
    }
}

// attention epilogue: block=row, thread=output dim (DO==256==blockDim)
__global__ __launch_bounds__(256) void gat_k(
    const float* __restrict__ hl, const float* __restrict__ hr,
    const int* __restrict__ nbr, const float* __restrict__ att,
    const float* __restrict__ bias, float* __restrict__ out)
{
    __shared__ int src[NSRC];
    __shared__ float eP[NSRC][4];
    __shared__ float eS[NSRC];
    const int i = blockIdx.x, t = threadIdx.x;
    if (t < KNB) src[t] = nbr[(size_t)i * KNB + t];
    if (t == KNB) src[KNB] = i;   // self-loop appended last
    __syncthreads();
    const float at  = att[t];
    const float hrv = hr[(size_t)i * DO + t];
    float hlv[NSRC];
#pragma unroll
    for (int k = 0; k < NSRC; ++k) {
        const float v = hl[(size_t)src[k] * DO + t];
        hlv[k] = v;
        const float z = v + hrv;
        float p = (z > 0.f ? z : NEG * z) * at;
#pragma unroll
        for (int off = 32; off >= 1; off >>= 1) p += __shfl_xor(p, off);
        if ((t & 63) == 0) eP[k][t >> 6] = p;
    }
    __syncthreads();
    if (t < NSRC) eS[t] = eP[t][0] + eP[t][1] + eP[t][2] + eP[t][3];
    __syncthreads();
    float m = eS[0];
#pragma unroll
    for (int k = 1; k < NSRC; ++k) m = fmaxf(m, eS[k]);
    float w[NSRC];
    float ssum = 0.f;
#pragma unroll
    for (int k = 0; k < NSRC; ++k) { w[k] = expf(eS[k] - m); ssum += w[k]; }
    const float inv = 1.f / ssum;
    float o = bias[t];
#pragma unroll
    for (int k = 0; k < NSRC; ++k) o = fmaf(w[k] * inv, hlv[k], o);
    out[(size_t)i * DO + t] = o;
}

extern "C" void kernel_launch(void* const* d_in, const int* in_sizes, int n_in,
                              void* d_out, int out_size, void* d_ws, size_t ws_size,
                              hipStream_t stream) {
    const float* x    = (const float*)d_in[0];
    const float* Wl   = (const float*)d_in[1];
    const float* bl   = (const float*)d_in[2];
    const float* Wr   = (const float*)d_in[3];
    const float* br   = (const float*)d_in[4];
    const float* att  = (const float*)d_in[5];
    const float* bias = (const float*)d_in[6];
    float* out = (float*)d_out;

    char* ws = (char*)d_ws;
    // layout (bytes); hl/hr alias the keys region (keys fully consumed by
    // knn_merge_k before hgemm_k writes hl/hr, stream-ordered):
    unsigned short* aF  = (unsigned short*)(ws + 0);          //  5,120,000
    unsigned short* Bhi = (unsigned short*)(ws + 5120000);    //  2,621,440
    unsigned short* Blo = (unsigned short*)(ws + 7741440);    //  2,621,440
    double* sq64 = (double*)(ws + 10362880);                  //     80,000
    float*  sq32 = (float*)(ws + 10442880);                   //     40,960
    int*    cand = (int*)(ws + 10483840);                     //  2,560,000
    int*    nbr  = (int*)(ws + 13043840);                     //  1,280,000
    unsigned* keys = (unsigned*)(ws + 14323840);              // 38,400,000
    float*  hl   = (float*)(ws + 14323840);                   // 10,240,000 (alias)
    float*  hr   = (float*)(ws + 24563840);                   // 10,240,000 (alias)
    // total = 52,723,840 bytes

    bsplit_k<<<dim3(NP2 / 2), 256, 0, stream>>>(x, Bhi, Blo);
    asplit_k<<<dim3(NN / 2), 256, 0, stream>>>(x, aF);
    sqrow_k<<<dim3(NP2 / RB), 256, 0, stream>>>(x, sq64, sq32);
    knn_partial_k<<<dim3(NN / RB, NCHUNK), 256, 0, stream>>>(aF, Bhi, Blo, sq32, keys);
    knn_merge_k<<<dim3(NN), 64, 0, stream>>>(keys, cand);
    rerank_k<<<dim3(NN), 64, 0, stream>>>(x, sq64, cand, nbr);
    hgemm_k<<<dim3(NN / RB), 256, 0, stream>>>(x, Wl, bl, Wr, br, hl, hr);
    gat_k<<<dim3(NN), 256, 0, stream>>>(hl, hr, nbr, att, bias, out);
}